// Round 1
// baseline (3111.647 us; speedup 1.0000x reference)
//
#include <hip/hip_runtime.h>
#include <math.h>

#define H_IN 256
#define W_IN 256
#define HO 128
#define WO 128
#define CIN 128
#define CO_OFF 1152
#define CO_MSK 576
#define NG 64

// ---------------------------------------------------------------------------
// Conv kernel: computes offset (1152 ch) and mask (576 ch, sigmoid) outputs
// of a 3x3 stride-2 pad-1 conv over x (B=2, C=128, 256,256) -> 128x128.
// Implicit GEMM tiling: 64 co x 128 wo per block (one b, one ho row),
// K = 128 ci x 9 taps, staged in LDS in 8-channel chunks.
// ---------------------------------------------------------------------------
__global__ __launch_bounds__(256) void conv_offmask(
    const float* __restrict__ x,
    const float* __restrict__ w_off, const float* __restrict__ b_off,
    const float* __restrict__ w_msk, const float* __restrict__ b_msk,
    float* __restrict__ offs, float* __restrict__ mask)
{
  const int co0 = blockIdx.x * 64;          // 27 tiles: 0..17 offset, 18..26 mask
  const int ho  = blockIdx.y & 127;
  const int b   = blockIdx.y >> 7;

  __shared__ float sW[72][64];              // [ci_l*9+k][co_l]
  __shared__ float sX[8][3][260];           // [ci_l][kh][ix_local], 258 used

  const int tid = threadIdx.x;
  const int tx = tid & 15;                  // wo direction (8 outputs, stride 16)
  const int ty = tid >> 4;                  // co direction (4 outputs, co_l = ty*4+i)

  const bool is_mask = (co0 >= CO_OFF);
  const float* wsrc = is_mask ? w_msk : w_off;
  const int co_base = is_mask ? (co0 - CO_OFF) : co0;

  const int iy0 = ho * 2 - 1;

  float acc[4][8];
  #pragma unroll
  for (int i = 0; i < 4; i++)
    #pragma unroll
    for (int j = 0; j < 8; j++) acc[i][j] = 0.f;

  for (int ci0 = 0; ci0 < CIN; ci0 += 8) {
    __syncthreads();
    // stage weights: 64 co x 72 k-elements
    for (int idx = tid; idx < 64 * 72; idx += 256) {
      int co_l = idx / 72;
      int kk = idx - co_l * 72;
      sW[kk][co_l] = wsrc[(size_t)(co_base + co_l) * 1152 + ci0 * 9 + kk];
    }
    // stage input patch: 8 ch x 3 rows x 258 cols (ix = -1 .. 256, zero-padded OOB)
    for (int idx = tid; idx < 8 * 3 * 258; idx += 256) {
      int ci_l = idx / 774;
      int rem = idx - ci_l * 774;
      int r = rem / 258;
      int cc = rem - r * 258;
      int iy = iy0 + r;
      int ix = cc - 1;
      float v = 0.f;
      if (iy >= 0 && iy < H_IN && ix >= 0 && ix < W_IN)
        v = x[((size_t)(b * CIN + ci0 + ci_l) * H_IN + iy) * W_IN + ix];
      sX[ci_l][r][cc] = v;
    }
    __syncthreads();

    for (int ci_l = 0; ci_l < 8; ci_l++) {
      #pragma unroll
      for (int k = 0; k < 9; k++) {
        const int kh = k / 3, kw = k - kh * 3;
        const int kk = ci_l * 9 + k;
        const float4 av = *reinterpret_cast<const float4*>(&sW[kk][ty * 4]);
        #pragma unroll
        for (int j = 0; j < 8; j++) {
          float xv = sX[ci_l][kh][(tx + j * 16) * 2 + kw];
          acc[0][j] = fmaf(av.x, xv, acc[0][j]);
          acc[1][j] = fmaf(av.y, xv, acc[1][j]);
          acc[2][j] = fmaf(av.z, xv, acc[2][j]);
          acc[3][j] = fmaf(av.w, xv, acc[3][j]);
        }
      }
    }
  }

  const float* bsrc = is_mask ? b_msk : b_off;
  #pragma unroll
  for (int i = 0; i < 4; i++) {
    int co = co_base + ty * 4 + i;
    float bias = bsrc[co];
    #pragma unroll
    for (int j = 0; j < 8; j++) {
      int wo = tx + j * 16;
      float v = acc[i][j] + bias;
      if (is_mask) {
        v = 1.f / (1.f + expf(-v));
        mask[((size_t)(b * CO_MSK + co) * HO + ho) * WO + wo] = v;
      } else {
        offs[((size_t)(b * CO_OFF + co) * HO + ho) * WO + wo] = v;
      }
    }
  }
}

// ---------------------------------------------------------------------------
// Deformable gather + per-group 2x2x9 einsum.
// One thread per (b, g, ho, wo); computes both output channels of group g.
// ---------------------------------------------------------------------------
__global__ __launch_bounds__(256) void deform(
    const float* __restrict__ x, const float* __restrict__ offs,
    const float* __restrict__ mask, const float* __restrict__ wd,
    float* __restrict__ out)
{
  const int bid = blockIdx.x;               // B * G * (HO/2) = 8192
  const int hp = bid & 63;
  const int g  = (bid >> 6) & 63;
  const int b  = bid >> 12;
  const int tid = threadIdx.x;
  const int wo = tid & 127;
  const int ho = hp * 2 + (tid >> 7);

  __shared__ float swd[36];                 // wg[g, o(2), cg(2), k(9)]
  if (tid < 36) swd[tid] = wd[g * 36 + tid];
  __syncthreads();

  const float* xg = x + ((size_t)(b * CIN + g * 2)) * (H_IN * W_IN);
  float acc0 = 0.f, acc1 = 0.f;
  const int pbase = ((b * CO_OFF + g * 18) * HO + ho) * WO + wo;
  const int mbase = ((b * CO_MSK + g * 9) * HO + ho) * WO + wo;

  #pragma unroll
  for (int k = 0; k < 9; k++) {
    float dy = offs[pbase + (2 * k) * (HO * WO)];
    float dx = offs[pbase + (2 * k + 1) * (HO * WO)];
    float m  = mask[mbase + k * (HO * WO)];
    float py = dy + (float)(ho * 2 - 1 + k / 3);
    float px = dx + (float)(wo * 2 - 1 + k % 3);
    float y0f = floorf(py), x0f = floorf(px);
    float wy = py - y0f, wx = px - x0f;
    float v0 = 0.f, v1 = 0.f;
    #pragma unroll
    for (int t = 0; t < 4; t++) {
      float yc = y0f + (float)(t >> 1);
      float xc = x0f + (float)(t & 1);
      float wgt = ((t >> 1) ? wy : 1.f - wy) * ((t & 1) ? wx : 1.f - wx);
      if (yc >= 0.f && yc <= (float)(H_IN - 1) && xc >= 0.f && xc <= (float)(W_IN - 1)) {
        int idx = (int)yc * W_IN + (int)xc;
        v0 += wgt * xg[idx];
        v1 += wgt * xg[H_IN * W_IN + idx];
      }
    }
    float w00 = swd[0 * 18 + 0 * 9 + k];
    float w01 = swd[0 * 18 + 1 * 9 + k];
    float w10 = swd[1 * 18 + 0 * 9 + k];
    float w11 = swd[1 * 18 + 1 * 9 + k];
    acc0 += m * (w00 * v0 + w01 * v1);
    acc1 += m * (w10 * v0 + w11 * v1);
  }

  out[((size_t)(b * CIN + g * 2 + 0) * HO + ho) * WO + wo] = acc0;
  out[((size_t)(b * CIN + g * 2 + 1) * HO + ho) * WO + wo] = acc1;
}

extern "C" void kernel_launch(void* const* d_in, const int* in_sizes, int n_in,
                              void* d_out, int out_size, void* d_ws, size_t ws_size,
                              hipStream_t stream) {
  const float* x     = (const float*)d_in[0];
  const float* w_off = (const float*)d_in[1];
  const float* b_off = (const float*)d_in[2];
  const float* w_msk = (const float*)d_in[3];
  const float* b_msk = (const float*)d_in[4];
  const float* w_def = (const float*)d_in[5];
  float* out = (float*)d_out;

  float* offs = (float*)d_ws;                                  // 2*1152*128*128 f32
  float* mask = offs + (size_t)2 * CO_OFF * HO * WO;           // 2*576*128*128 f32

  dim3 cgrid(27, 256);   // 27 co-tiles x (B*Ho)
  conv_offmask<<<cgrid, 256, 0, stream>>>(x, w_off, b_off, w_msk, b_msk, offs, mask);

  deform<<<2 * NG * (HO / 2), 256, 0, stream>>>(x, offs, mask, w_def, out);
}

// Round 2
// 511.980 us; speedup vs baseline: 6.0777x; 6.0777x over previous
//
#include <hip/hip_runtime.h>
#include <math.h>

#define B_SZ 2
#define H_IN 256
#define W_IN 256
#define HO 128
#define WO 128
#define CIN 128
#define CO_OFF 1152
#define CO_MSK 576
#define NG 64
#define KD 1152           // GEMM K (ci*9 + kh*3 + kw)
#define KBY 2304          // K row bytes in bf16
#define ND 32768          // GEMM N = B*HO*WO
#define MPAD 1792         // 1728 padded to 14*128

typedef short short8 __attribute__((ext_vector_type(8)));
typedef float f32x4 __attribute__((ext_vector_type(4)));
typedef const unsigned int __attribute__((address_space(1))) gcu32;
typedef unsigned int __attribute__((address_space(3))) slu32;

__device__ __forceinline__ unsigned short f2b(float v) {
  union { float f; unsigned u; } a; a.f = v;
  unsigned r = a.u + 0x7FFF + ((a.u >> 16) & 1);
  return (unsigned short)(r >> 16);
}
__device__ __forceinline__ float b2f(unsigned short u) {
  union { unsigned u; float f; } a; a.u = ((unsigned)u) << 16;
  return a.f;
}

// ---------------------------------------------------------------------------
// im2col, transposed: col[n][k] bf16, n = b*16384 + ho*128 + wo, k = ci*9+kh*3+kw
// ---------------------------------------------------------------------------
__global__ __launch_bounds__(256) void im2col_k(const float* __restrict__ x,
                                                unsigned short* __restrict__ col) {
  int i = blockIdx.x * 256 + threadIdx.x;        // N*K = 37,748,736 exact
  int n = i / KD;
  int k = i - n * KD;
  int wo = n & 127, ho = (n >> 7) & 127, b = n >> 14;
  int ci = k / 9, t = k - ci * 9;
  int kh = t / 3, kw = t - kh * 3;
  int iy = 2 * ho - 1 + kh, ix = 2 * wo - 1 + kw;
  float v = 0.f;
  if ((unsigned)iy < H_IN && (unsigned)ix < W_IN)
    v = x[(((size_t)b * CIN + ci) * H_IN + iy) * W_IN + ix];
  col[i] = f2b(v);
}

// ---------------------------------------------------------------------------
// Pack both conv weights into bf16 [MPAD][KD]; rows 1728..1791 zero.
// ---------------------------------------------------------------------------
__global__ __launch_bounds__(256) void pack_w(const float* __restrict__ w_off,
                                              const float* __restrict__ w_msk,
                                              unsigned short* __restrict__ wb) {
  int i = blockIdx.x * 256 + threadIdx.x;        // MPAD*KD = 2,064,384 exact
  int m = i / KD;
  float v = 0.f;
  if (m < CO_OFF) v = w_off[i];
  else if (m < 1728) v = w_msk[i - CO_OFF * KD];
  wb[i] = f2b(v);
}

// ---------------------------------------------------------------------------
// MFMA GEMM: C[m][n] = sum_k wb[m][k]*col[n][k]; 128x128 tile, BK=64, 4 waves.
// global_load_lds(16B) with pre-swizzled source; ds_read swizzle (row&7)<<4.
// Epilogue: +bias, sigmoid for mask rows, bf16 store into [b][co][ho*wo].
// ---------------------------------------------------------------------------
__global__ __launch_bounds__(256, 2) void gemm_conv(
    const unsigned short* __restrict__ wb, const unsigned short* __restrict__ col,
    const float* __restrict__ b_off, const float* __restrict__ b_msk,
    unsigned short* __restrict__ offs, unsigned short* __restrict__ mask)
{
  __shared__ __attribute__((aligned(128))) char sA[16384];   // [128 m][64 k] bf16, swizzled
  __shared__ __attribute__((aligned(128))) char sB[16384];   // [128 n][64 k] bf16, swizzled

  // XCD-aware bijective swizzle (3584 % 8 == 0, 448 per XCD)
  int bid = blockIdx.x;
  int swz = (bid & 7) * 448 + (bid >> 3);
  const int m0 = (swz % 14) * 128;
  const int n0 = (swz / 14) * 128;

  const int tid = threadIdx.x;
  const int l = tid & 63;
  const int w = tid >> 6;

  // staging: wave w<2 -> A, w>=2 -> B; (w&1) selects row-half 0..63 / 64..127
  // chunk j covers 8 rows (1024 B LDS); lane l: row = 8j + (l>>3), kb = (l&7)*16
  const int rl = l >> 3;
  const int kbsw = ((l & 7) << 4) ^ (rl << 4);   // inverse-swizzled source k-byte
  const char* gA = (const char*)wb  + (size_t)(m0 + (w & 1) * 64 + rl) * KBY + kbsw;
  const char* gB = (const char*)col + (size_t)(n0 + (w & 1) * 64 + rl) * KBY + kbsw;
  const char* g = (w < 2) ? gA : gB;
  char* sbase = ((w < 2) ? sA : sB) + (w & 1) * 8192;

  const int fr = l & 15;
  const int kq = (l >> 4) * 16;                  // k-byte quarter offset
  const int wm = (w >> 1) * 64;
  const int wn = (w & 1) * 64;

  f32x4 acc[4][4];
  #pragma unroll
  for (int a = 0; a < 4; a++)
    #pragma unroll
    for (int c = 0; c < 4; c++) acc[a][c] = (f32x4)(0.f);

  for (int ks = 0; ks < 18; ks++) {
    __syncthreads();
    #pragma unroll
    for (int j = 0; j < 8; j++) {
      __builtin_amdgcn_global_load_lds((gcu32*)(g + (size_t)j * 8 * KBY),
                                       (slu32*)(sbase + j * 1024), 16, 0, 0);
    }
    g += 128;                                    // next 64 k (bf16) = 128 B
    __syncthreads();

    #pragma unroll
    for (int kk = 0; kk < 2; kk++) {
      short8 af[4], bfr[4];
      #pragma unroll
      for (int mi = 0; mi < 4; mi++) {
        int row = wm + mi * 16 + fr;
        int off = row * 128 + ((kk * 64 + kq) ^ ((row & 7) << 4));
        af[mi] = *(const short8*)(sA + off);
      }
      #pragma unroll
      for (int ni = 0; ni < 4; ni++) {
        int row = wn + ni * 16 + fr;
        int off = row * 128 + ((kk * 64 + kq) ^ ((row & 7) << 4));
        bfr[ni] = *(const short8*)(sB + off);
      }
      #pragma unroll
      for (int mi = 0; mi < 4; mi++)
        #pragma unroll
        for (int ni = 0; ni < 4; ni++)
          asm("v_mfma_f32_16x16x32_bf16 %0, %1, %2, %0"
              : "+v"(acc[mi][ni]) : "v"(af[mi]), "v"(bfr[ni]));
    }
  }

  // epilogue: C[m][n], m = m0+wm+mi*16+(l>>4)*4+r, n = n0+wn+ni*16+(l&15)
  const int b = n0 >> 14;
  const int nl0 = (n0 & 16383) + wn;
  const int rq = (l >> 4) * 4;
  #pragma unroll
  for (int mi = 0; mi < 4; mi++) {
    #pragma unroll
    for (int r = 0; r < 4; r++) {
      int m = m0 + wm + mi * 16 + rq + r;
      if (m < 1728) {
        bool ismk = (m >= CO_OFF);
        float bias = ismk ? b_msk[m - CO_OFF] : b_off[m];
        unsigned short* dst = ismk
            ? mask + (((size_t)(b * CO_MSK + (m - CO_OFF))) << 14)
            : offs + (((size_t)(b * CO_OFF + m)) << 14);
        #pragma unroll
        for (int ni = 0; ni < 4; ni++) {
          float v = acc[mi][ni][r] + bias;
          if (ismk) v = 1.f / (1.f + expf(-v));
          dst[nl0 + ni * 16 + fr] = f2b(v);
        }
      }
    }
  }
}

// ---------------------------------------------------------------------------
// Deformable gather + per-group 2x2x9 einsum (offs/mask now bf16).
// ---------------------------------------------------------------------------
__global__ __launch_bounds__(256) void deform(
    const float* __restrict__ x, const unsigned short* __restrict__ offs,
    const unsigned short* __restrict__ mask, const float* __restrict__ wd,
    float* __restrict__ out)
{
  const int bid = blockIdx.x;               // B * G * (HO/2) = 8192
  const int hp = bid & 63;
  const int g  = (bid >> 6) & 63;
  const int b  = bid >> 12;
  const int tid = threadIdx.x;
  const int wo = tid & 127;
  const int ho = hp * 2 + (tid >> 7);

  __shared__ float swd[36];
  if (tid < 36) swd[tid] = wd[g * 36 + tid];
  __syncthreads();

  const float* xg = x + ((size_t)(b * CIN + g * 2)) * (H_IN * W_IN);
  float acc0 = 0.f, acc1 = 0.f;
  const int pbase = ((b * CO_OFF + g * 18) * HO + ho) * WO + wo;
  const int mbase = ((b * CO_MSK + g * 9) * HO + ho) * WO + wo;

  #pragma unroll
  for (int k = 0; k < 9; k++) {
    float dy = b2f(offs[pbase + (2 * k) * (HO * WO)]);
    float dx = b2f(offs[pbase + (2 * k + 1) * (HO * WO)]);
    float m  = b2f(mask[mbase + k * (HO * WO)]);
    float py = dy + (float)(ho * 2 - 1 + k / 3);
    float px = dx + (float)(wo * 2 - 1 + k % 3);
    float y0f = floorf(py), x0f = floorf(px);
    float wy = py - y0f, wx = px - x0f;
    float v0 = 0.f, v1 = 0.f;
    #pragma unroll
    for (int t = 0; t < 4; t++) {
      float yc = y0f + (float)(t >> 1);
      float xc = x0f + (float)(t & 1);
      float wgt = ((t >> 1) ? wy : 1.f - wy) * ((t & 1) ? wx : 1.f - wx);
      if (yc >= 0.f && yc <= (float)(H_IN - 1) && xc >= 0.f && xc <= (float)(W_IN - 1)) {
        int idx = (int)yc * W_IN + (int)xc;
        v0 += wgt * xg[idx];
        v1 += wgt * xg[H_IN * W_IN + idx];
      }
    }
    acc0 += m * (swd[0 * 18 + 0 * 9 + k] * v0 + swd[0 * 18 + 1 * 9 + k] * v1);
    acc1 += m * (swd[1 * 18 + 0 * 9 + k] * v0 + swd[1 * 18 + 1 * 9 + k] * v1);
  }

  out[((size_t)(b * CIN + g * 2 + 0) * HO + ho) * WO + wo] = acc0;
  out[((size_t)(b * CIN + g * 2 + 1) * HO + ho) * WO + wo] = acc1;
}

extern "C" void kernel_launch(void* const* d_in, const int* in_sizes, int n_in,
                              void* d_out, int out_size, void* d_ws, size_t ws_size,
                              hipStream_t stream) {
  const float* x     = (const float*)d_in[0];
  const float* w_off = (const float*)d_in[1];
  const float* b_off = (const float*)d_in[2];
  const float* w_msk = (const float*)d_in[3];
  const float* b_msk = (const float*)d_in[4];
  const float* w_def = (const float*)d_in[5];
  float* out = (float*)d_out;

  unsigned short* col  = (unsigned short*)d_ws;                 // [N][K]   75.5 MB
  unsigned short* wbf  = col  + (size_t)ND * KD;                // [MPAD][K] 4.1 MB
  unsigned short* offs = wbf  + (size_t)MPAD * KD;              // bf16      75.5 MB
  unsigned short* mask = offs + (size_t)B_SZ * CO_OFF * HO * WO;// bf16      37.7 MB

  im2col_k<<<(ND * KD) / 256, 256, 0, stream>>>(x, col);
  pack_w<<<(MPAD * KD) / 256, 256, 0, stream>>>(w_off, w_msk, wbf);
  gemm_conv<<<14 * 256, 256, 0, stream>>>(wbf, col, b_off, b_msk, offs, mask);
  deform<<<B_SZ * NG * (HO / 2), 256, 0, stream>>>(x, offs, mask, w_def, out);
}

// Round 3
// 437.903 us; speedup vs baseline: 7.1058x; 1.1692x over previous
//
#include <hip/hip_runtime.h>
#include <math.h>

#define B_SZ 2
#define H_IN 256
#define W_IN 256
#define HO 128
#define WO 128
#define CIN 128
#define CO_OFF 1152
#define CO_MSK 576
#define NG 64
#define KD 1152           // GEMM K (ci*9 + kh*3 + kw)
#define KBY 2304          // K row bytes in bf16
#define ND 32768          // GEMM N = B*HO*WO
#define MPAD 1792         // 1728 padded to 14*128
#define NT 18             // K-tiles (1152/64)
#define BUFSZ 49152       // one LDS buffer: A 16KB + B 32KB

typedef short short8 __attribute__((ext_vector_type(8)));
typedef float f32x4 __attribute__((ext_vector_type(4)));
typedef const unsigned int __attribute__((address_space(1))) gcu32;
typedef unsigned int __attribute__((address_space(3))) slu32;

__device__ __forceinline__ unsigned short f2b(float v) {
  union { float f; unsigned u; } a; a.f = v;
  unsigned r = a.u + 0x7FFF + ((a.u >> 16) & 1);
  return (unsigned short)(r >> 16);
}
__device__ __forceinline__ float b2f(unsigned short u) {
  union { unsigned u; float f; } a; a.u = ((unsigned)u) << 16;
  return a.f;
}

// ---------------------------------------------------------------------------
// im2col, transposed: col[n][k] bf16, n = b*16384 + ho*128 + wo, k = ci*9+kh*3+kw
// Block = (b, ho, cg of 16 ci). Stage 16ci x 3 rows x 256 cols in LDS (float4
// coalesced), then each thread emits 72 contiguous bf16 (9 x 16B stores).
// ---------------------------------------------------------------------------
__global__ __launch_bounds__(256) void im2col_k(const float* __restrict__ x,
                                                unsigned short* __restrict__ col) {
  __shared__ float sX[16][3][260];   // [ci_l][r][ix]; [256] = ix=-1 slot (zero)

  const int bid = blockIdx.x;        // 2048 = b(2) * ho(128) * cg(8)
  const int cg = bid & 7;
  const int ho = (bid >> 3) & 127;
  const int b  = bid >> 10;
  const int tid = threadIdx.x;

  // stage interior: 16ci x 3r x 64 float4 = 3072 -> 12 per thread
  #pragma unroll
  for (int i = 0; i < 12; i++) {
    int idx = i * 256 + tid;
    int ci_l = idx / 192;
    int rem = idx - ci_l * 192;
    int r = rem >> 6;
    int j = rem & 63;
    int iy = 2 * ho - 1 + r;
    float4 v = make_float4(0.f, 0.f, 0.f, 0.f);
    if ((unsigned)iy < H_IN)
      v = *reinterpret_cast<const float4*>(
          x + (((size_t)(b * CIN + cg * 16 + ci_l)) * H_IN + iy) * W_IN + j * 4);
    *reinterpret_cast<float4*>(&sX[ci_l][r][j * 4]) = v;
  }
  if (tid < 48) {                    // zero the ix=-1 slots (16ci x 3r)
    int ci_l = tid / 3, r = tid - ci_l * 3;
    sX[ci_l][r][256] = 0.f;
  }
  __syncthreads();

  const int wo = tid & 127;
  const int h = tid >> 7;            // ci-oct within this cg
  float vals[72];
  #pragma unroll
  for (int ci = 0; ci < 8; ci++)
    #pragma unroll
    for (int kh = 0; kh < 3; kh++)
      #pragma unroll
      for (int kw = 0; kw < 3; kw++) {
        int ix = 2 * wo - 1 + kw;
        int lx = (ix < 0) ? 256 : ix;            // ix in [-1,255]
        vals[ci * 9 + kh * 3 + kw] = sX[h * 8 + ci][kh][lx];
      }

  const int n = (b << 14) | (ho << 7) | wo;
  short8* dst = reinterpret_cast<short8*>(col + (size_t)n * KD + cg * 144 + h * 72);
  #pragma unroll
  for (int c = 0; c < 9; c++) {
    short8 o;
    #pragma unroll
    for (int e = 0; e < 8; e++) o[e] = (short)f2b(vals[c * 8 + e]);
    dst[c] = o;
  }
}

// ---------------------------------------------------------------------------
// Pack both conv weights into bf16 [MPAD][KD]; rows 1728..1791 zero.
// ---------------------------------------------------------------------------
__global__ __launch_bounds__(256) void pack_w(const float* __restrict__ w_off,
                                              const float* __restrict__ w_msk,
                                              unsigned short* __restrict__ wb) {
  int i = blockIdx.x * 256 + threadIdx.x;        // MPAD*KD = 2,064,384 exact
  int m = i / KD;
  float v = 0.f;
  if (m < CO_OFF) v = w_off[i];
  else if (m < 1728) v = w_msk[i - CO_OFF * KD];
  wb[i] = f2b(v);
}

// ---------------------------------------------------------------------------
// Pipelined MFMA GEMM: C[m][n] = sum_k wb[m][k]*col[n][k].
// BM=128, BN=256, BK=64, 8 waves (2M x 4N, 64x64 each), 3 LDS buffers.
// Loads issued 2 K-tiles ahead; one barrier + one counted vmcnt(6) per K-tile;
// setprio(1) around MFMA clusters. Both-sides XOR swizzle (row&7)<<4.
// Epilogue: +bias, sigmoid for mask rows, bf16 store.
// ---------------------------------------------------------------------------
__global__ __launch_bounds__(512, 1) void gemm_conv(
    const unsigned short* __restrict__ wb, const unsigned short* __restrict__ col,
    const float* __restrict__ b_off, const float* __restrict__ b_msk,
    unsigned short* __restrict__ offs, unsigned short* __restrict__ mask)
{
  __shared__ __attribute__((aligned(128))) char lds[3 * BUFSZ];  // 144 KiB

  // XCD-aware bijective swizzle: 1792 % 8 == 0, 224 per XCD
  const int bid = blockIdx.x;
  const int swz = (bid & 7) * 224 + (bid >> 3);
  const int m0 = (swz % 14) * 128;
  const int n0 = (swz / 14) * 256;

  const int tid = threadIdx.x;
  const int l = tid & 63;
  const int w = tid >> 6;

  // --- staging slots: 48 wave-chunks (8 rows x 128B each); wave w owns 6 ---
  // chunk c<16: A rows 8c..8c+7 ; c>=16: B rows 8(c-16)..
  const int rl = l >> 3;                          // row within chunk
  const int kbsw = ((l & 7) << 4) ^ (rl << 4);    // inverse-swizzled src k-byte
  const char* srcp[6];
  int ldof[6];
  #pragma unroll
  for (int s = 0; s < 6; s++) {
    int c = w * 6 + s;
    if (c < 16) {
      srcp[s] = (const char*)wb + (size_t)(m0 + c * 8 + rl) * KBY + kbsw;
      ldof[s] = c * 1024;
    } else {
      srcp[s] = (const char*)col + (size_t)(n0 + (c - 16) * 8 + rl) * KBY + kbsw;
      ldof[s] = 16384 + (c - 16) * 1024;
    }
  }

  // prologue: stage tile 0 -> buf0, tile 1 -> buf1 (issue order matters: t0 first)
  #pragma unroll
  for (int s = 0; s < 6; s++)
    __builtin_amdgcn_global_load_lds((gcu32*)srcp[s], (slu32*)(lds + ldof[s]), 16, 0, 0);
  #pragma unroll
  for (int s = 0; s < 6; s++)
    __builtin_amdgcn_global_load_lds((gcu32*)(srcp[s] + 128),
                                     (slu32*)(lds + BUFSZ + ldof[s]), 16, 0, 0);
  #pragma unroll
  for (int s = 0; s < 6; s++) srcp[s] += 256;     // now pointing at tile 2

  const int fr = l & 15;
  const int kq = (l >> 4) << 4;
  const int wm = (w >> 2) * 64;                   // 2 m-groups
  const int wn = (w & 3) * 64;                    // 4 n-groups

  f32x4 acc[4][4];
  #pragma unroll
  for (int a = 0; a < 4; a++)
    #pragma unroll
    for (int c = 0; c < 4; c++) acc[a][c] = (f32x4)(0.f);

  int rb = 0, nb = 2;
  for (int t = 0; t < NT; t++) {
    if (t < NT - 1) asm volatile("s_waitcnt vmcnt(6)" ::: "memory");
    else            asm volatile("s_waitcnt vmcnt(0)" ::: "memory");
    __builtin_amdgcn_s_barrier();

    const char* bufA = lds + rb * BUFSZ;
    const char* bufB = bufA + 16384;
    char* nbuf = lds + nb * BUFSZ;

    if (t < NT - 2) {
      #pragma unroll
      for (int s = 0; s < 3; s++) {
        __builtin_amdgcn_global_load_lds((gcu32*)srcp[s], (slu32*)(nbuf + ldof[s]), 16, 0, 0);
        srcp[s] += 128;
      }
    }

    // kk = 0
    short8 af[4], bf[4];
    #pragma unroll
    for (int mi = 0; mi < 4; mi++) {
      int row = wm + mi * 16 + fr;
      af[mi] = *(const short8*)(bufA + row * 128 + (kq ^ ((row & 7) << 4)));
    }
    #pragma unroll
    for (int ni = 0; ni < 4; ni++) {
      int row = wn + ni * 16 + fr;
      bf[ni] = *(const short8*)(bufB + row * 128 + (kq ^ ((row & 7) << 4)));
    }
    __builtin_amdgcn_s_setprio(1);
    #pragma unroll
    for (int mi = 0; mi < 4; mi++)
      #pragma unroll
      for (int ni = 0; ni < 4; ni++)
        asm("v_mfma_f32_16x16x32_bf16 %0, %1, %2, %0"
            : "+v"(acc[mi][ni]) : "v"(af[mi]), "v"(bf[ni]));
    __builtin_amdgcn_s_setprio(0);

    if (t < NT - 2) {
      #pragma unroll
      for (int s = 3; s < 6; s++) {
        __builtin_amdgcn_global_load_lds((gcu32*)srcp[s], (slu32*)(nbuf + ldof[s]), 16, 0, 0);
        srcp[s] += 128;
      }
    }

    // kk = 1
    short8 af2[4], bf2[4];
    #pragma unroll
    for (int mi = 0; mi < 4; mi++) {
      int row = wm + mi * 16 + fr;
      af2[mi] = *(const short8*)(bufA + row * 128 + ((64 + kq) ^ ((row & 7) << 4)));
    }
    #pragma unroll
    for (int ni = 0; ni < 4; ni++) {
      int row = wn + ni * 16 + fr;
      bf2[ni] = *(const short8*)(bufB + row * 128 + ((64 + kq) ^ ((row & 7) << 4)));
    }
    __builtin_amdgcn_s_setprio(1);
    #pragma unroll
    for (int mi = 0; mi < 4; mi++)
      #pragma unroll
      for (int ni = 0; ni < 4; ni++)
        asm("v_mfma_f32_16x16x32_bf16 %0, %1, %2, %0"
            : "+v"(acc[mi][ni]) : "v"(af2[mi]), "v"(bf2[ni]));
    __builtin_amdgcn_s_setprio(0);

    rb = (rb == 2) ? 0 : rb + 1;
    nb = (nb == 2) ? 0 : nb + 1;
  }

  // epilogue: m = m0+wm+mi*16+(l>>4)*4+r, n = n0+wn+ni*16+(l&15)
  const int b = n0 >> 14;
  const int nl0 = (n0 & 16383) + wn;
  const int rq = (l >> 4) * 4;
  #pragma unroll
  for (int mi = 0; mi < 4; mi++) {
    #pragma unroll
    for (int r = 0; r < 4; r++) {
      int m = m0 + wm + mi * 16 + rq + r;
      if (m < 1728) {
        bool ismk = (m >= CO_OFF);
        float bias = ismk ? b_msk[m - CO_OFF] : b_off[m];
        unsigned short* dst = ismk
            ? mask + (((size_t)(b * CO_MSK + (m - CO_OFF))) << 14)
            : offs + (((size_t)(b * CO_OFF + m)) << 14);
        #pragma unroll
        for (int ni = 0; ni < 4; ni++) {
          float v = acc[mi][ni][r] + bias;
          if (ismk) v = 1.f / (1.f + expf(-v));
          dst[nl0 + ni * 16 + fr] = f2b(v);
        }
      }
    }
  }
}

// ---------------------------------------------------------------------------
// Deformable gather + per-group 2x2x9 einsum (offs/mask bf16).
// ---------------------------------------------------------------------------
__global__ __launch_bounds__(256) void deform(
    const float* __restrict__ x, const unsigned short* __restrict__ offs,
    const unsigned short* __restrict__ mask, const float* __restrict__ wd,
    float* __restrict__ out)
{
  const int bid = blockIdx.x;               // B * G * (HO/2) = 8192
  const int hp = bid & 63;
  const int g  = (bid >> 6) & 63;
  const int b  = bid >> 12;
  const int tid = threadIdx.x;
  const int wo = tid & 127;
  const int ho = hp * 2 + (tid >> 7);

  __shared__ float swd[36];
  if (tid < 36) swd[tid] = wd[g * 36 + tid];
  __syncthreads();

  const float* xg = x + ((size_t)(b * CIN + g * 2)) * (H_IN * W_IN);
  float acc0 = 0.f, acc1 = 0.f;
  const int pbase = ((b * CO_OFF + g * 18) * HO + ho) * WO + wo;
  const int mbase = ((b * CO_MSK + g * 9) * HO + ho) * WO + wo;

  #pragma unroll
  for (int k = 0; k < 9; k++) {
    float dy = b2f(offs[pbase + (2 * k) * (HO * WO)]);
    float dx = b2f(offs[pbase + (2 * k + 1) * (HO * WO)]);
    float m  = b2f(mask[mbase + k * (HO * WO)]);
    float py = dy + (float)(ho * 2 - 1 + k / 3);
    float px = dx + (float)(wo * 2 - 1 + k % 3);
    float y0f = floorf(py), x0f = floorf(px);
    float wy = py - y0f, wx = px - x0f;
    float v0 = 0.f, v1 = 0.f;
    #pragma unroll
    for (int t = 0; t < 4; t++) {
      float yc = y0f + (float)(t >> 1);
      float xc = x0f + (float)(t & 1);
      float wgt = ((t >> 1) ? wy : 1.f - wy) * ((t & 1) ? wx : 1.f - wx);
      if (yc >= 0.f && yc <= (float)(H_IN - 1) && xc >= 0.f && xc <= (float)(W_IN - 1)) {
        int idx = (int)yc * W_IN + (int)xc;
        v0 += wgt * xg[idx];
        v1 += wgt * xg[H_IN * W_IN + idx];
      }
    }
    acc0 += m * (swd[0 * 18 + 0 * 9 + k] * v0 + swd[0 * 18 + 1 * 9 + k] * v1);
    acc1 += m * (swd[1 * 18 + 0 * 9 + k] * v0 + swd[1 * 18 + 1 * 9 + k] * v1);
  }

  out[((size_t)(b * CIN + g * 2 + 0) * HO + ho) * WO + wo] = acc0;
  out[((size_t)(b * CIN + g * 2 + 1) * HO + ho) * WO + wo] = acc1;
}

extern "C" void kernel_launch(void* const* d_in, const int* in_sizes, int n_in,
                              void* d_out, int out_size, void* d_ws, size_t ws_size,
                              hipStream_t stream) {
  const float* x     = (const float*)d_in[0];
  const float* w_off = (const float*)d_in[1];
  const float* b_off = (const float*)d_in[2];
  const float* w_msk = (const float*)d_in[3];
  const float* b_msk = (const float*)d_in[4];
  const float* w_def = (const float*)d_in[5];
  float* out = (float*)d_out;

  unsigned short* col  = (unsigned short*)d_ws;                 // [N][K]   75.5 MB
  unsigned short* wbf  = col  + (size_t)ND * KD;                // [MPAD][K] 4.1 MB
  unsigned short* offs = wbf  + (size_t)MPAD * KD;              // bf16      75.5 MB
  unsigned short* mask = offs + (size_t)B_SZ * CO_OFF * HO * WO;// bf16      37.7 MB

  im2col_k<<<2048, 256, 0, stream>>>(x, col);
  pack_w<<<(MPAD * KD) / 256, 256, 0, stream>>>(w_off, w_msk, wbf);
  gemm_conv<<<14 * 128, 512, 0, stream>>>(wbf, col, b_off, b_msk, offs, mask);
  deform<<<B_SZ * NG * (HO / 2), 256, 0, stream>>>(x, offs, mask, w_def, out);
}

// Round 4
// 396.286 us; speedup vs baseline: 7.8520x; 1.1050x over previous
//
#include <hip/hip_runtime.h>
#include <math.h>

#define B_SZ 2
#define H_IN 256
#define W_IN 256
#define HO 128
#define WO 128
#define CIN 128
#define CO_OFF 1152
#define CO_MSK 576
#define NG 64
#define KD 1152           // GEMM K, reordered: k = (kh*3+kw)*128 + ci
#define KBY 2304          // K row bytes in bf16
#define ND 32768          // GEMM N = B*HO*WO
#define MPAD 1792         // 1728 padded to 14*128
#define NT 18             // K-tiles (1152/64)
#define XTROW_B 66048     // 258*128*2 bytes per padded iy row
#define XTIMG_B 17040384  // 258*XTROW_B bytes per image

typedef short short8 __attribute__((ext_vector_type(8)));
typedef float f32x4 __attribute__((ext_vector_type(4)));
typedef const unsigned int __attribute__((address_space(1))) gcu32;
typedef unsigned int __attribute__((address_space(3))) slu32;

__device__ __forceinline__ unsigned short f2b(float v) {
  union { float f; unsigned u; } a; a.f = v;
  unsigned r = a.u + 0x7FFF + ((a.u >> 16) & 1);
  return (unsigned short)(r >> 16);
}
__device__ __forceinline__ float b2f(unsigned short u) {
  union { unsigned u; float f; } a; a.u = ((unsigned)u) << 16;
  return a.f;
}

// ---------------------------------------------------------------------------
// x (NCHW f32) -> x_t [b][iy+1][ix+1][ci] bf16, zero-padded borders.
// Block = (b, iy_t). Interior: LDS-transpose 32ci x 64ix chunks.
// ---------------------------------------------------------------------------
__global__ __launch_bounds__(256) void xpose(const float* __restrict__ x,
                                             unsigned short* __restrict__ xt) {
  const int bid = blockIdx.x;            // 2*258
  const int iyt = bid % 258;
  const int b = bid / 258;
  const int tid = threadIdx.x;
  char* rowp = (char*)xt + (size_t)b * XTIMG_B + (size_t)iyt * XTROW_B;
  const int iy = iyt - 1;
  const short8 z8 = {0, 0, 0, 0, 0, 0, 0, 0};

  if (iy < 0 || iy >= H_IN) {            // full zero row: 66048 B
    for (int i = tid; i < 4128; i += 256)
      *reinterpret_cast<short8*>(rowp + i * 16) = z8;
    return;
  }
  if (tid < 32) {                        // ix = -1 and 256 pad columns
    int c = tid & 15;
    *reinterpret_cast<short8*>(rowp + ((tid >> 4) ? 257 * 256 : 0) + c * 16) = z8;
  }

  __shared__ float sX[32][68];
  const float* xb = x + (size_t)b * CIN * 65536 + iy * 256;
  for (int ci0 = 0; ci0 < CIN; ci0 += 32) {
    for (int ix0 = 0; ix0 < W_IN; ix0 += 64) {
      __syncthreads();
      {
        int ci_l = tid >> 3, f4 = tid & 7;
        const float4* src = reinterpret_cast<const float4*>(
            xb + (size_t)(ci0 + ci_l) * 65536 + ix0);
        *reinterpret_cast<float4*>(&sX[ci_l][f4 * 4]) = src[f4];
        *reinterpret_cast<float4*>(&sX[ci_l][(f4 + 8) * 4]) = src[f4 + 8];
      }
      __syncthreads();
      {
        int ix_l = tid >> 2, cq = (tid & 3) * 8;
        short8 o;
        #pragma unroll
        for (int e = 0; e < 8; e++) o[e] = (short)f2b(sX[cq + e][ix_l]);
        *reinterpret_cast<short8*>(rowp + (ix0 + ix_l + 1) * 256 + (ci0 + cq) * 2) = o;
      }
    }
  }
}

// ---------------------------------------------------------------------------
// Pack weights bf16 [MPAD][KD], K reordered: wb[m][tap*128+ci] = w[m][ci*9+tap]
// ---------------------------------------------------------------------------
__global__ __launch_bounds__(256) void pack_w(const float* __restrict__ w_off,
                                              const float* __restrict__ w_msk,
                                              unsigned short* __restrict__ wb) {
  int i = blockIdx.x * 256 + threadIdx.x;        // MPAD*KD exact
  int m = i / KD;
  int k = i - m * KD;
  int tap = k >> 7, ci = k & 127;
  int src = ci * 9 + tap;
  float v = 0.f;
  if (m < CO_OFF) v = w_off[(size_t)m * KD + src];
  else if (m < 1728) v = w_msk[(size_t)(m - CO_OFF) * KD + src];
  wb[i] = f2b(v);
}

// ---------------------------------------------------------------------------
// Implicit-conv MFMA GEMM: C[m][n] = sum_k wb[m][k] * im2col(x_t)[n][k].
// BM=128, BN=128, BK=64, 4 waves (w<2 stage A, w>=2 stage B directly from x_t).
// 2-phase double-buffer: STAGE(t+1) issued before compute(t), one barrier/tile.
// Both-sides XOR swizzle (row&7)<<4; epilogue bias+sigmoid, bf16 store.
// ---------------------------------------------------------------------------
__global__ __launch_bounds__(256, 2) void gemm_conv(
    const unsigned short* __restrict__ wb, const unsigned short* __restrict__ xt,
    const float* __restrict__ b_off, const float* __restrict__ b_msk,
    unsigned short* __restrict__ offs, unsigned short* __restrict__ mask)
{
  __shared__ __attribute__((aligned(128))) char lds[2][32768];  // [buf][A 16K | B 16K]

  // XCD-aware bijective swizzle: 3584 % 8 == 0, 448 per XCD
  const int bid = blockIdx.x;
  const int swz = (bid & 7) * 448 + (bid >> 3);
  const int m0 = (swz % 14) * 128;
  const int n0 = (swz / 14) * 128;
  const int ho = (n0 >> 7) & 127;
  const int b  = n0 >> 14;

  const int tid = threadIdx.x;
  const int l = tid & 63;
  const int w = tid >> 6;

  const int rl = l >> 3;                          // row within 8-row chunk
  const int kbsw = ((l & 7) << 4) ^ (rl << 4);    // inverse-swizzled src k-byte

  // A source (waves 0,1): rows m0 + (w&1)*64 + j*8 + rl, advance 128 B per tile
  const char* gA = (const char*)wb + (size_t)(m0 + (w & 1) * 64 + rl) * KBY + kbsw;
  // B source (waves 2,3): x_t, wo = (w&1)*64 + j*8 + rl
  const char* pB = (const char*)xt + (size_t)b * XTIMG_B
                 + ((w & 1) * 64 + rl) * 512 + kbsw;
  const int sb_off = (w & 1) * 8192;              // LDS half offset within A or B

  const int fr = l & 15;
  const int kq = (l >> 4) << 4;
  const int wm = (w >> 1) * 64;
  const int wn = (w & 1) * 64;

  f32x4 acc[4][4];
  #pragma unroll
  for (int a = 0; a < 4; a++)
    #pragma unroll
    for (int c = 0; c < 4; c++) acc[a][c] = (f32x4)(0.f);

  // stage tile kt into lds[bf]
  auto STAGE = [&](int kt, int bf) {
    if (w < 2) {
      const char* pa = gA + kt * 128;
      #pragma unroll
      for (int j = 0; j < 8; j++)
        __builtin_amdgcn_global_load_lds((gcu32*)(pa + (size_t)j * 8 * KBY),
                                         (slu32*)(&lds[bf][sb_off + j * 1024]), 16, 0, 0);
    } else {
      int tap = kt >> 1;
      int kh = (tap * 11) >> 5;                   // tap/3 for 0..8
      int kw = tap - 3 * kh;
      const char* pb = pB + (2 * ho + kh) * XTROW_B + kw * 256 + (kt & 1) * 128;
      #pragma unroll
      for (int j = 0; j < 8; j++)
        __builtin_amdgcn_global_load_lds((gcu32*)(pb + j * 4096),
                                         (slu32*)(&lds[bf][16384 + sb_off + j * 1024]), 16, 0, 0);
    }
  };

  STAGE(0, 0);
  __syncthreads();

  int cur = 0;
  for (int t = 0; t < NT; t++) {
    if (t < NT - 1) STAGE(t + 1, cur ^ 1);        // issue loads, then compute

    const char* bufA = &lds[cur][0];
    const char* bufB = &lds[cur][16384];
    #pragma unroll
    for (int kk = 0; kk < 2; kk++) {
      short8 af[4], bf[4];
      #pragma unroll
      for (int mi = 0; mi < 4; mi++) {
        int row = wm + mi * 16 + fr;
        af[mi] = *(const short8*)(bufA + row * 128 + ((kk * 64 + kq) ^ ((row & 7) << 4)));
      }
      #pragma unroll
      for (int ni = 0; ni < 4; ni++) {
        int row = wn + ni * 16 + fr;
        bf[ni] = *(const short8*)(bufB + row * 128 + ((kk * 64 + kq) ^ ((row & 7) << 4)));
      }
      __builtin_amdgcn_s_setprio(1);
      #pragma unroll
      for (int mi = 0; mi < 4; mi++)
        #pragma unroll
        for (int ni = 0; ni < 4; ni++)
          asm("v_mfma_f32_16x16x32_bf16 %0, %1, %2, %0"
              : "+v"(acc[mi][ni]) : "v"(af[mi]), "v"(bf[ni]));
      __builtin_amdgcn_s_setprio(0);
    }
    __syncthreads();                              // drains vm+lgkm: next buf ready
    cur ^= 1;
  }

  // epilogue: m = m0+wm+mi*16+(l>>4)*4+r, n = n0+wn+ni*16+(l&15)
  const int nl0 = (n0 & 16383) + wn;
  const int rq = (l >> 4) * 4;
  #pragma unroll
  for (int mi = 0; mi < 4; mi++) {
    #pragma unroll
    for (int r = 0; r < 4; r++) {
      int m = m0 + wm + mi * 16 + rq + r;
      if (m < 1728) {
        bool ismk = (m >= CO_OFF);
        float bias = ismk ? b_msk[m - CO_OFF] : b_off[m];
        unsigned short* dst = ismk
            ? mask + (((size_t)(b * CO_MSK + (m - CO_OFF))) << 14)
            : offs + (((size_t)(b * CO_OFF + m)) << 14);
        #pragma unroll
        for (int ni = 0; ni < 4; ni++) {
          float v = acc[mi][ni][r] + bias;
          if (ismk) v = 1.f / (1.f + expf(-v));
          dst[nl0 + ni * 16 + fr] = f2b(v);
        }
      }
    }
  }
}

// ---------------------------------------------------------------------------
// Deformable gather + per-group 2x2x9 einsum (offs/mask bf16). Unchanged.
// ---------------------------------------------------------------------------
__global__ __launch_bounds__(256) void deform(
    const float* __restrict__ x, const unsigned short* __restrict__ offs,
    const unsigned short* __restrict__ mask, const float* __restrict__ wd,
    float* __restrict__ out)
{
  const int bid = blockIdx.x;               // B * G * (HO/2) = 8192
  const int hp = bid & 63;
  const int g  = (bid >> 6) & 63;
  const int b  = bid >> 12;
  const int tid = threadIdx.x;
  const int wo = tid & 127;
  const int ho = hp * 2 + (tid >> 7);

  __shared__ float swd[36];
  if (tid < 36) swd[tid] = wd[g * 36 + tid];
  __syncthreads();

  const float* xg = x + ((size_t)(b * CIN + g * 2)) * (H_IN * W_IN);
  float acc0 = 0.f, acc1 = 0.f;
  const int pbase = ((b * CO_OFF + g * 18) * HO + ho) * WO + wo;
  const int mbase = ((b * CO_MSK + g * 9) * HO + ho) * WO + wo;

  #pragma unroll
  for (int k = 0; k < 9; k++) {
    float dy = b2f(offs[pbase + (2 * k) * (HO * WO)]);
    float dx = b2f(offs[pbase + (2 * k + 1) * (HO * WO)]);
    float m  = b2f(mask[mbase + k * (HO * WO)]);
    float py = dy + (float)(ho * 2 - 1 + k / 3);
    float px = dx + (float)(wo * 2 - 1 + k % 3);
    float y0f = floorf(py), x0f = floorf(px);
    float wy = py - y0f, wx = px - x0f;
    float v0 = 0.f, v1 = 0.f;
    #pragma unroll
    for (int t = 0; t < 4; t++) {
      float yc = y0f + (float)(t >> 1);
      float xc = x0f + (float)(t & 1);
      float wgt = ((t >> 1) ? wy : 1.f - wy) * ((t & 1) ? wx : 1.f - wx);
      if (yc >= 0.f && yc <= (float)(H_IN - 1) && xc >= 0.f && xc <= (float)(W_IN - 1)) {
        int idx = (int)yc * W_IN + (int)xc;
        v0 += wgt * xg[idx];
        v1 += wgt * xg[H_IN * W_IN + idx];
      }
    }
    acc0 += m * (swd[0 * 18 + 0 * 9 + k] * v0 + swd[0 * 18 + 1 * 9 + k] * v1);
    acc1 += m * (swd[1 * 18 + 0 * 9 + k] * v0 + swd[1 * 18 + 1 * 9 + k] * v1);
  }

  out[((size_t)(b * CIN + g * 2 + 0) * HO + ho) * WO + wo] = acc0;
  out[((size_t)(b * CIN + g * 2 + 1) * HO + ho) * WO + wo] = acc1;
}

extern "C" void kernel_launch(void* const* d_in, const int* in_sizes, int n_in,
                              void* d_out, int out_size, void* d_ws, size_t ws_size,
                              hipStream_t stream) {
  const float* x     = (const float*)d_in[0];
  const float* w_off = (const float*)d_in[1];
  const float* b_off = (const float*)d_in[2];
  const float* w_msk = (const float*)d_in[3];
  const float* b_msk = (const float*)d_in[4];
  const float* w_def = (const float*)d_in[5];
  float* out = (float*)d_out;

  unsigned short* xt   = (unsigned short*)d_ws;                 // 34.1 MB
  unsigned short* wbf  = xt + (size_t)B_SZ * 258 * 258 * CIN;   // 4.1 MB
  unsigned short* offs = wbf + (size_t)MPAD * KD;               // 75.5 MB
  unsigned short* mask = offs + (size_t)B_SZ * CO_OFF * HO * WO;// 37.7 MB

  xpose<<<B_SZ * 258, 256, 0, stream>>>(x, xt);
  pack_w<<<(MPAD * KD) / 256, 256, 0, stream>>>(w_off, w_msk, wbf);
  gemm_conv<<<14 * 256, 256, 0, stream>>>(wbf, xt, b_off, b_msk, offs, mask);
  deform<<<B_SZ * NG * (HO / 2), 256, 0, stream>>>(x, offs, mask, w_def, out);
}